// Round 1
// baseline (276.503 us; speedup 1.0000x reference)
//
#include <hip/hip_runtime.h>
#include <math.h>

#define BB 4
#define NN 4096
#define DD 64
#define KK 8
#define CH 2   // j-chunks per row (for grid parallelism: 4*64*2 = 512 blocks)

__device__ __forceinline__ float tau_of(const float* __restrict__ temp) {
  float tc = temp[0];
  tc = fminf(fmaxf(tc, -5.0f), 5.0f);
  return expf(tc);
}

// insert candidate into sorted (ascending key) top-8; strict < => on equal keys
// the earlier-arrived (smaller index, given ascending-j arrival) entry stays ahead.
__device__ __forceinline__ void ins_strict(float (&kk)[KK], int (&kj)[KK], float key, int j) {
  if (key < kk[KK - 1]) {
    kk[KK - 1] = key; kj[KK - 1] = j;
#pragma unroll
    for (int m = KK - 1; m > 0; --m) {
      if (kk[m] < kk[m - 1]) {
        float tk = kk[m]; kk[m] = kk[m - 1]; kk[m - 1] = tk;
        int tj = kj[m]; kj[m] = kj[m - 1]; kj[m - 1] = tj;
      }
    }
  }
}

// lexicographic (key asc, idx asc) insertion — arrival order independent.
__device__ __forceinline__ void ins_lex(float (&kk)[KK], int (&kj)[KK], float key, int j) {
  if (key < kk[KK - 1] || (key == kk[KK - 1] && j < kj[KK - 1])) {
    kk[KK - 1] = key; kj[KK - 1] = j;
#pragma unroll
    for (int m = KK - 1; m > 0; --m) {
      bool sw = (kk[m] < kk[m - 1]) || (kk[m] == kk[m - 1] && kj[m] < kj[m - 1]);
      if (sw) {
        float tk = kk[m]; kk[m] = kk[m - 1]; kk[m - 1] = tk;
        int tj = kj[m]; kj[m] = kj[m - 1]; kj[m - 1] = tj;
      }
    }
  }
}

// ---------------- Kernel 1: MLP (3 layers) + row squared norms ----------------
__device__ __forceinline__ void mlp_layer(const float (*bin)[68], float (*bout)[68],
                                          float (*wT)[68], float* bias,
                                          const float* __restrict__ Wg,
                                          const float* __restrict__ bg,
                                          bool dorelu, int t) {
  const int rr = t >> 2;          // output row o (for W staging)
  const int dc = (t & 3) << 4;    // input chunk
  {
    const float* wsrc = Wg + rr * DD + dc;
#pragma unroll
    for (int q = 0; q < 16; ++q) wT[dc + q][rr] = wsrc[q];  // wT[i][o] = W[o][i]
    if (t < DD) bias[t] = bg[t];
  }
  __syncthreads();
  const int tg = t & 15, og = t >> 4;
  float acc[4][4];
#pragma unroll
  for (int r = 0; r < 4; ++r)
#pragma unroll
    for (int c = 0; c < 4; ++c) acc[r][c] = 0.f;
#pragma unroll 4
  for (int i = 0; i < DD; ++i) {
    const float4 av = *reinterpret_cast<const float4*>(&bin[i][tg << 2]);
    const float4 wv = *reinterpret_cast<const float4*>(&wT[i][og << 2]);
    float aa[4] = {av.x, av.y, av.z, av.w};
    float ww[4] = {wv.x, wv.y, wv.z, wv.w};
#pragma unroll
    for (int r = 0; r < 4; ++r)
#pragma unroll
      for (int c = 0; c < 4; ++c) acc[r][c] += aa[r] * ww[c];
  }
#pragma unroll
  for (int r = 0; r < 4; ++r)
#pragma unroll
    for (int c = 0; c < 4; ++c) {
      float v = acc[r][c] + bias[(og << 2) + c];
      if (dorelu) v = fmaxf(v, 0.f);
      bout[(og << 2) + c][(tg << 2) + r] = v;  // transposed for next layer
    }
  __syncthreads();
}

__global__ __launch_bounds__(256) void k_mlp(
    const float* __restrict__ x,
    const float* __restrict__ W1, const float* __restrict__ b1,
    const float* __restrict__ W2, const float* __restrict__ b2,
    const float* __restrict__ W3, const float* __restrict__ b3,
    float* __restrict__ h, float* __restrict__ sqo) {
  __shared__ float bufA[DD][68];
  __shared__ float bufB[DD][68];
  __shared__ float wT[DD][68];
  __shared__ float bias[DD];
  const int t = threadIdx.x;
  const size_t tok0 = (size_t)blockIdx.x * 64;  // flat token base over [B*N]
  const int rr = t >> 2;
  const int dc = (t & 3) << 4;
  {
    const float* src = x + (tok0 + rr) * DD + dc;
#pragma unroll
    for (int q = 0; q < 16; ++q) bufA[dc + q][rr] = src[q];  // transposed [d][tok]
  }
  mlp_layer(bufA, bufB, wT, bias, W1, b1, true, t);
  mlp_layer(bufB, bufA, wT, bias, W2, b2, true, t);
  mlp_layer(bufA, bufB, wT, bias, W3, b3, false, t);
  {
    float s = 0.f;
    float* dst = h + (tok0 + rr) * DD + dc;
#pragma unroll
    for (int q = 0; q < 16; ++q) {
      float v = bufB[dc + q][rr];
      dst[q] = v;
      s += v * v;
    }
    s += __shfl_xor(s, 1);
    s += __shfl_xor(s, 2);
    if ((t & 3) == 0) sqo[tok0 + rr] = s;
  }
}

// ------------- Kernel 2: fused distance tiles + per-row top-8 (per chunk) -------------
__global__ __launch_bounds__(256) void k_disttopk(
    const float* __restrict__ h, const float* __restrict__ sq,
    const float* __restrict__ temp,
    float* __restrict__ pk, int* __restrict__ pj) {
  __shared__ float hiT[DD][68];     // [d][row]
  __shared__ float hjT[DD][68];     // [d][col]
  __shared__ float sqi[64];
  __shared__ float sqj[64];
  __shared__ float distT[64][65];   // [row][col]

  const int t = threadIdx.x;
  const int bx = blockIdx.x;
  const int b = bx >> 7;
  const int rt = (bx >> 1) & 63;
  const int ch = bx & 1;
  const int i0 = rt << 6;
  const float* hb = h + (size_t)b * NN * DD;
  const float* sqb = sq + b * NN;
  const float tau = tau_of(temp);

  const int rr = t >> 2;
  const int dc = (t & 3) << 4;
  {
    const float* src = hb + (size_t)(i0 + rr) * DD + dc;
#pragma unroll
    for (int q = 0; q < 16; ++q) hiT[dc + q][rr] = src[q];
    if (t < 64) sqi[t] = sqb[i0 + t];
  }

  float kk[KK]; int kj[KK];
#pragma unroll
  for (int m = 0; m < KK; ++m) { kk[m] = 3.0e38f; kj[m] = 0x7fffffff; }

  const int row = t & 63;
  const int qq = t >> 6;  // scanner quarter
  const int jbase = ch * (NN / CH);

  for (int jt = 0; jt < (NN / CH) / 64; ++jt) {
    const int j0 = jbase + (jt << 6);
    __syncthreads();  // protects hiT (first iter) and hjT/distT reuse
    {
      const float* src = hb + (size_t)(j0 + rr) * DD + dc;
#pragma unroll
      for (int q = 0; q < 16; ++q) hjT[dc + q][rr] = src[q];
      if (t < 64) sqj[t] = sqb[j0 + t];
    }
    __syncthreads();

    const int tg = t & 15, og = t >> 4;
    float acc[4][4];
#pragma unroll
    for (int r = 0; r < 4; ++r)
#pragma unroll
      for (int c = 0; c < 4; ++c) acc[r][c] = 0.f;
#pragma unroll 4
    for (int d = 0; d < DD; ++d) {
      const float4 av = *reinterpret_cast<const float4*>(&hiT[d][tg << 2]);
      const float4 bv = *reinterpret_cast<const float4*>(&hjT[d][og << 2]);
      float aa[4] = {av.x, av.y, av.z, av.w};
      float ww[4] = {bv.x, bv.y, bv.z, bv.w};
#pragma unroll
      for (int r = 0; r < 4; ++r)
#pragma unroll
        for (int c = 0; c < 4; ++c) acc[r][c] += aa[r] * ww[c];
    }
    // dist = (sq_i + sq_j) - 2*dot, mirroring the reference's fp32 expression
    // tree exactly (no fp contraction).
#pragma unroll
    for (int r = 0; r < 4; ++r)
#pragma unroll
      for (int c = 0; c < 4; ++c) {
        float s2 = __fadd_rn(sqi[(tg << 2) + r], sqj[(og << 2) + c]);
        float dd2 = __fsub_rn(s2, __fmul_rn(2.0f, acc[r][c]));
        distT[(tg << 2) + r][(og << 2) + c] = dd2;
      }
    __syncthreads();
    // scan: 4 threads per row, 16 candidates each, ascending j per thread
#pragma unroll
    for (int s = 0; s < 16; ++s) {
      const int jj = (qq << 4) + s;
      const float key = __fmul_rn(distT[row][jj], tau);
      ins_strict(kk, kj, key, j0 + jj);
    }
  }
  __syncthreads();
  // dump the 4 quarter lists per row to LDS (reuse distT/hjT), merge lexicographically
  float* lk = &distT[0][0];                      // 2048 floats needed <= 64*65
  int* lj = reinterpret_cast<int*>(&hjT[0][0]);  // 2048 ints needed <= 64*68
#pragma unroll
  for (int m = 0; m < KK; ++m) {
    lk[((row << 2) + qq) * KK + m] = kk[m];
    lj[((row << 2) + qq) * KK + m] = kj[m];
  }
  __syncthreads();
  if (t < 64) {
    float fk[KK]; int fj[KK];
#pragma unroll
    for (int m = 0; m < KK; ++m) { fk[m] = 3.0e38f; fj[m] = 0x7fffffff; }
    for (int q2 = 0; q2 < 4; ++q2) {
#pragma unroll
      for (int m = 0; m < KK; ++m) {
        float key = lk[((t << 2) + q2) * KK + m];
        int j = lj[((t << 2) + q2) * KK + m];
        ins_lex(fk, fj, key, j);
      }
    }
    const size_t base = ((size_t)(b * NN + i0 + t) * CH + ch) * KK;
#pragma unroll
    for (int m = 0; m < KK; ++m) { pk[base + m] = fk[m]; pj[base + m] = fj[m]; }
  }
}

// ------------- Kernel 3: merge chunks, recompute dng, emit edges + logprobs -------------
__global__ __launch_bounds__(256) void k_final(
    const float* __restrict__ h, const float* __restrict__ pk,
    const int* __restrict__ pj, const float* __restrict__ temp,
    float* __restrict__ out) {
  const int gid = blockIdx.x * 256 + threadIdx.x;  // 0..B*N-1
  const int b = gid >> 12;
  const int i = gid & (NN - 1);
  const float tau = tau_of(temp);

  float fk[KK]; int fj[KK];
#pragma unroll
  for (int m = 0; m < KK; ++m) { fk[m] = 3.0e38f; fj[m] = 0x7fffffff; }
  const size_t base = (size_t)(b * NN + i) * CH * KK;
#pragma unroll
  for (int s = 0; s < CH * KK; ++s) {
    ins_lex(fk, fj, pk[base + s], pj[base + s]);
  }

  const float* hi = h + (size_t)(b * NN + i) * DD;
  float4 xi[16];
#pragma unroll
  for (int q = 0; q < 16; ++q) xi[q] = *reinterpret_cast<const float4*>(hi + (q << 2));

  float* oute = out;                                 // edges region (as float)
  float* outl = out + (size_t)BB * NN * KK * 2;      // logprobs region
#pragma unroll
  for (int m = 0; m < KK; ++m) {
    const int j = fj[m];
    const float* hj = h + (size_t)(b * NN + j) * DD;
    float dng = 0.f;
#pragma unroll
    for (int q = 0; q < 16; ++q) {
      const float4 vj = *reinterpret_cast<const float4*>(hj + (q << 2));
      float dx = xi[q].x - vj.x; dng += dx * dx;
      float dy = xi[q].y - vj.y; dng += dy * dy;
      float dz = xi[q].z - vj.z; dng += dz * dz;
      float dw = xi[q].w - vj.w; dng += dw * dw;
    }
    const size_t e = (size_t)(b * NN + i) * KK + m;
    oute[e * 2 + 0] = (float)j;   // neighbor index
    oute[e * 2 + 1] = (float)i;   // source row
    outl[e] = -__fmul_rn(dng, tau);
  }
}

extern "C" void kernel_launch(void* const* d_in, const int* in_sizes, int n_in,
                              void* d_out, int out_size, void* d_ws, size_t ws_size,
                              hipStream_t stream) {
  const float* x  = (const float*)d_in[0];
  const float* W1 = (const float*)d_in[1];
  const float* b1 = (const float*)d_in[2];
  const float* W2 = (const float*)d_in[3];
  const float* b2 = (const float*)d_in[4];
  const float* W3 = (const float*)d_in[5];
  const float* b3 = (const float*)d_in[6];
  const float* temp = (const float*)d_in[7];
  (void)in_sizes; (void)n_in; (void)out_size; (void)ws_size;

  float* ws = (float*)d_ws;
  float* h  = ws;                                  // B*N*D floats
  float* sq = h + (size_t)BB * NN * DD;            // B*N floats
  float* pk = sq + (size_t)BB * NN;                // B*N*CH*K floats
  int*   pj = (int*)(pk + (size_t)BB * NN * CH * KK);  // B*N*CH*K ints
  float* out = (float*)d_out;

  k_mlp<<<BB * NN / 64, 256, 0, stream>>>(x, W1, b1, W2, b2, W3, b3, h, sq);
  k_disttopk<<<BB * (NN / 64) * CH, 256, 0, stream>>>(h, sq, temp, pk, pj);
  k_final<<<BB * NN / 256, 256, 0, stream>>>(h, pk, pj, temp, out);
}